// Round 10
// baseline (191.712 us; speedup 1.0000x reference)
//
#include <hip/hip_runtime.h>
#include <hip/hip_bf16.h>

// BoundaryPredictor2: B=8, L=1500, D=1024, H=8, HD=128, S=300. fp32 in/out.
// Pipeline (5 dispatches):
//   1. prep: Wv/Wo->bf16, qk = q@Wk (bf16), per-batch segment scan
//   2. ln_score (wave-per-row): LN stats + 8 head scores. qk held in
//      REGISTERS (not LDS); head reduction via exchange-half transpose
//      butterfly (10 shfls vs 48); rows with t >= alen skipped (never read).
//      Writes only scores + (mu,rs).
//   3. pool: per-(b,s) softmax + weighted accumulation, re-normalizing fp32
//      hidden rows (L3-resident) via murs + per-thread gamma/beta.
//   4. headgemm: pooled[bs, h*128+d] = hpool[h][bs,:] . Wv[h*128+d,:]
//   5. ogemm: out = pooled @ Wo^T
// V-GEMM eliminated (pooling commutes with V-proj); K-GEMM eliminated (qk).
#define BPK_B 8
#define BPK_L 1500
#define BPK_D 1024
#define BPK_H 8
#define BPK_S 300
#define BPK_EPS 1e-5f
#define BPK_M (BPK_B * BPK_L)      // 12000 token rows
#define BPK_MS (BPK_B * BPK_S)     // 2400 pooled rows
#define BPK_MS_TILES 19            // ceil(2400/128)
#define BPK_HP_ROWS 2432           // 19*128 rows per head (hpool padding)
#define BPK_PO_PAD 3072            // 24*128 rows (O-GEMM A padding)

typedef __hip_bfloat16 bf16;
typedef __bf16 bf16x8 __attribute__((ext_vector_type(8)));
typedef float v4f __attribute__((ext_vector_type(4)));

static __device__ __forceinline__ float bf_lo(unsigned u) {
    return __uint_as_float((u & 0xffffu) << 16);
}
static __device__ __forceinline__ float bf_hi(unsigned u) {
    return __uint_as_float((u >> 16) << 16);
}
static __device__ __forceinline__ void bpk_store(float v, float* p) { *p = v; }
static __device__ __forceinline__ void bpk_store(float v, bf16* p) { *p = __float2bfloat16(v); }
static __device__ __forceinline__ uint2 pack4bf(float a, float b, float c, float d) {
    union { bf16 h[4]; uint2 u; } pk;
    pk.h[0] = __float2bfloat16(a); pk.h[1] = __float2bfloat16(b);
    pk.h[2] = __float2bfloat16(c); pk.h[3] = __float2bfloat16(d);
    return pk.u;
}

// async global->LDS, 16B per lane, lds dest = wave-uniform base + lane*16
#define BPK_GL2LDS(gsrc, ldst)                                                 \
    __builtin_amdgcn_global_load_lds(                                          \
        (const __attribute__((address_space(1))) void*)(gsrc),                 \
        (__attribute__((address_space(3))) void*)(ldst), 16, 0, 0)

// ---------------------------------------------------------------------------
// Kernel 1: fused prep. blocks 0..2047: Wv/Wo fp32->bf16; 2048..2079: qk
// precompute; 2080..2087: per-batch parallel segment scan.
// ---------------------------------------------------------------------------
__global__ __launch_bounds__(256) void bpk_prep_kernel(
    const float* __restrict__ Wv, const float* __restrict__ Wo,
    const float* __restrict__ lq, const float* __restrict__ Wk,
    const float* __restrict__ boundaries, const float* __restrict__ lengths,
    bf16* __restrict__ wvb, bf16* __restrict__ wob, bf16* __restrict__ qkb,
    int* __restrict__ seg_start, int* __restrict__ seg_cnt) {
    __shared__ unsigned char flags[1536];
    __shared__ int st_sh[BPK_S + 2];
    __shared__ int wsumi[4];
    int blk = blockIdx.x;
    int tid = threadIdx.x;
    if (blk < 2048) {
        const float* s = blk < 1024 ? Wv : Wo;
        bf16* d = blk < 1024 ? wvb : wob;
        int i = ((blk & 1023) * 256 + tid) * 4;
        float4 v = *(const float4*)(s + i);
        *(uint2*)(d + i) = pack4bf(v.x, v.y, v.z, v.w);
        return;
    }
    if (blk < 2080) {
        int o = (blk - 2048) * 256 + tid;       // 0..8191
        int h = o >> 10, k = o & 1023;
        const float* wr = Wk + (size_t)(h * 128) * BPK_D + k;
        const float* qr = lq + h * 128;
        float s = 0.f;
        #pragma unroll 8
        for (int d = 0; d < 128; d++)
            s += qr[d] * wr[(size_t)d * BPK_D];
        qkb[o] = __float2bfloat16(s);
        return;
    }
    // segment scan, b = blk - 2080
    int b = blk - 2080;
    int alen = (int)(lengths[b] * (float)BPK_L);   // trunc == .astype(int32)
    const float* bd = boundaries + (size_t)b * BPK_L;
    for (int t = tid; t < 1536; t += 256)
        flags[t] = (t < BPK_L && bd[t] >= 0.5f) ? 1 : 0;
    for (int s = tid; s < BPK_S + 2; s += 256) st_sh[s] = BPK_L;
    __syncthreads();
    int base = tid * 6;
    int lsum = 0;
    #pragma unroll
    for (int j = 0; j < 6; j++) lsum += flags[base + j];
    int lane = tid & 63, wid = tid >> 6;
    int scan = lsum;
    #pragma unroll
    for (int off = 1; off < 64; off <<= 1) {
        int u = __shfl_up(scan, off);
        if (lane >= off) scan += u;
    }
    if (lane == 63) wsumi[wid] = scan;
    __syncthreads();
    int wbase = 0;
    for (int w = 0; w < wid; w++) wbase += wsumi[w];
    int run = wbase + scan - lsum;
    #pragma unroll
    for (int j = 0; j < 6; j++) {
        int t = base + j;
        if (t < BPK_L) {
            int sid = run;
            if ((t == 0 || flags[t - 1]) && sid <= BPK_S) st_sh[sid] = t;
            if (flags[t]) run++;
        }
    }
    __syncthreads();
    for (int s = tid; s < BPK_S; s += 256) {
        int st = st_sh[s];
        int e = min(st_sh[s + 1], alen);
        int s0 = min(st, alen);
        seg_start[b * BPK_S + s] = st;
        seg_cnt[b * BPK_S + s] = max(0, e - s0);
    }
}

// ---------------------------------------------------------------------------
// Kernel 2: LN stats + fused scores, wave-per-row, DS-pipe-minimized.
// - qk table held in registers (64 VGPR/lane), loaded once per wave.
// - Head dots reduced with exchange-half transpose butterfly: 4+2+1 shfls
//   fold 8 values into 1-per-lane (head = 4*b0 + (lane&2) + b2), then 3
//   shfls (xor 8/16/32) complete the 64-lane sum. 10 shfls vs 48.
// - Rows with t >= alen skipped entirely (their scores/murs are never read:
//   pool clips all segments to alen). ~25% traffic saved.
// ---------------------------------------------------------------------------
__global__ __launch_bounds__(256) void bpk_ln_score_kernel(
    const float* __restrict__ x, const float* __restrict__ gamma,
    const float* __restrict__ beta, const bf16* __restrict__ qkb,
    const float* __restrict__ lengths,
    float2* __restrict__ murs, float* __restrict__ scores) {
    int tid = threadIdx.x;
    int lane = tid & 63, wid = tid >> 6;
    float4 g[4], bb[4];
    uint2 qk[8][4];
    #pragma unroll
    for (int j = 0; j < 4; j++) {
        g[j]  = *(const float4*)(gamma + j * 256 + lane * 4);
        bb[j] = *(const float4*)(beta + j * 256 + lane * 4);
    }
    #pragma unroll
    for (int h = 0; h < 8; h++)
        #pragma unroll
        for (int j = 0; j < 4; j++)
            qk[h][j] = *(const uint2*)(qkb + h * BPK_D + j * 256 + lane * 4);
    float lv = (lane < BPK_B) ? lengths[lane] : 0.f;   // per-batch lengths
    const bool b0 = (lane & 1) != 0;
    const bool b1 = (lane & 2) != 0;
    const bool b2 = (lane & 4) != 0;
    const int head = 4 * (lane & 1) + (lane & 2) + ((lane >> 2) & 1);

    const int nwaves = gridDim.x * 4;
    for (int row = blockIdx.x * 4 + wid; row < BPK_M; row += nwaves) {
        int b = row / BPK_L, t = row - b * BPK_L;
        float alenf = __shfl(lv, b);
        if (t >= (int)(alenf * (float)BPK_L)) continue;   // wave-uniform skip
        const float* xr = x + (size_t)row * BPK_D;
        float4 f[4];
        float s = 0.f, sq = 0.f;
        #pragma unroll
        for (int j = 0; j < 4; j++) {
            f[j] = *(const float4*)(xr + j * 256 + lane * 4);
            s  += f[j].x + f[j].y + f[j].z + f[j].w;
            sq += f[j].x * f[j].x + f[j].y * f[j].y
                + f[j].z * f[j].z + f[j].w * f[j].w;
        }
        #pragma unroll
        for (int off = 1; off < 64; off <<= 1) {
            s  += __shfl_xor(s, off);
            sq += __shfl_xor(sq, off);
        }
        float mu = s * (1.0f / BPK_D);
        float var = sq * (1.0f / BPK_D) - mu * mu;
        float rs = rsqrtf(var + BPK_EPS);
        float p[8];
        #pragma unroll
        for (int h = 0; h < 8; h++) p[h] = 0.f;
        #pragma unroll
        for (int j = 0; j < 4; j++) {
            float h0 = (f[j].x - mu) * rs * g[j].x + bb[j].x;
            float h1 = (f[j].y - mu) * rs * g[j].y + bb[j].y;
            float h2 = (f[j].z - mu) * rs * g[j].z + bb[j].z;
            float h3 = (f[j].w - mu) * rs * g[j].w + bb[j].w;
            #pragma unroll
            for (int h = 0; h < 8; h++) {
                uint2 qv = qk[h][j];
                p[h] += h0 * bf_lo(qv.x) + h1 * bf_hi(qv.x)
                      + h2 * bf_lo(qv.y) + h3 * bf_hi(qv.y);
            }
        }
        // --- exchange-half transpose reduce (10 shfls) ---
        // step 1 (xor 1): even lanes keep heads 0-3, odd keep 4-7
        #pragma unroll
        for (int r = 0; r < 4; r++) {
            float send = b0 ? p[r] : p[r + 4];
            float recv = __shfl_xor(send, 1);
            p[r]     += b0 ? 0.f : recv;
            p[r + 4] += b0 ? recv : 0.f;
        }
        float q0 = b0 ? p[4] : p[0];
        float q1 = b0 ? p[5] : p[1];
        float q2 = b0 ? p[6] : p[2];
        float q3 = b0 ? p[7] : p[3];
        // step 2 (xor 2): bit1==0 keeps q0,q1; bit1==1 keeps q2,q3
        {
            float send = b1 ? q0 : q2;
            float recv = __shfl_xor(send, 2);
            q0 += b1 ? 0.f : recv;
            q2 += b1 ? recv : 0.f;
            send = b1 ? q1 : q3;
            recv = __shfl_xor(send, 2);
            q1 += b1 ? 0.f : recv;
            q3 += b1 ? recv : 0.f;
        }
        float a = b1 ? q2 : q0;
        float c = b1 ? q3 : q1;
        // step 3 (xor 4): bit2==0 keeps a (head base2), bit2==1 keeps c
        float send = b2 ? a : c;
        float recv = __shfl_xor(send, 4);
        float v = (b2 ? c : a) + recv;
        // steps 4-6: full 64-lane sum
        v += __shfl_xor(v, 8);
        v += __shfl_xor(v, 16);
        v += __shfl_xor(v, 32);
        if (lane < 8) {
            scores[((size_t)b * BPK_H + head) * BPK_L + t] =
                v * 0.088388347648318447f;
        } else if (lane == 8) {
            murs[row] = make_float2(mu, rs);
        }
    }
}

// ---------------------------------------------------------------------------
// Kernel 3: per-(b,s) softmax + weighted pooling into per-head hpool.
// Reads fp32 hidden rows (L3-resident after ln_score) and re-normalizes via
// murs + per-thread gamma/beta (thread owns dims 4t..4t+3). Wave 0 computes
// per-head max/sum (8 lanes/head, xor-reduce); weights chunked in LDS;
// 32 fp32 accumulators per thread. Empty segments -> zeros.
// ---------------------------------------------------------------------------
__global__ __launch_bounds__(256) void bpk_pool_kernel(
    const float* __restrict__ scores, const float* __restrict__ x,
    const float* __restrict__ gamma, const float* __restrict__ beta,
    const float2* __restrict__ murs,
    const int* __restrict__ seg_start, const int* __restrict__ seg_cnt,
    bf16* __restrict__ hpool) {
    int bs = blockIdx.x;                // = b*S + s
    int b = bs / BPK_S;
    int tid = threadIdx.x;
    int lane = tid & 63, wid = tid >> 6;
    __shared__ float minv[8][2];
    __shared__ float wls[8][128];
    int cnt = seg_cnt[bs], st = seg_start[bs];
    float4 g4 = *(const float4*)(gamma + tid * 4);
    float4 b4 = *(const float4*)(beta + tid * 4);
    float acc[8][4];
    #pragma unroll
    for (int h = 0; h < 8; h++)
        #pragma unroll
        for (int j = 0; j < 4; j++) acc[h][j] = 0.f;
    if (cnt > 0) {
        if (wid == 0) {
            int h = lane & 7, i0 = lane >> 3;   // 8 lanes per head
            const float* sc = scores + ((size_t)(b * 8 + h)) * BPK_L + st;
            float m = -1e30f;
            for (int i = i0; i < cnt; i += 8) m = fmaxf(m, sc[i]);
            #pragma unroll
            for (int off = 8; off < 64; off <<= 1) m = fmaxf(m, __shfl_xor(m, off));
            float l = 0.f;
            for (int i = i0; i < cnt; i += 8) l += __expf(sc[i] - m);
            #pragma unroll
            for (int off = 8; off < 64; off <<= 1) l += __shfl_xor(l, off);
            if (i0 == 0) { minv[h][0] = m; minv[h][1] = 1.0f / l; }
        }
        __syncthreads();
        for (int cb = 0; cb < cnt; cb += 128) {
            int cc = min(128, cnt - cb);
            int hh = tid >> 5, i0 = (tid & 31) * 4;
            #pragma unroll
            for (int j = 0; j < 4; j++) {
                int i = i0 + j;
                if (i < cc)
                    wls[hh][i] = __expf(scores[((size_t)(b * 8 + hh)) * BPK_L + st + cb + i]
                                        - minv[hh][0]) * minv[hh][1];
            }
            __syncthreads();
            const float* xp = x + (size_t)(b * BPK_L + st + cb) * BPK_D + tid * 4;
            const float2* mp = murs + (size_t)(b * BPK_L + st + cb);
            for (int i = 0; i < cc; i++) {
                float4 f = *(const float4*)(xp + (size_t)i * BPK_D);
                float2 mr = mp[i];
                float x0 = (f.x - mr.x) * mr.y * g4.x + b4.x;
                float x1 = (f.y - mr.x) * mr.y * g4.y + b4.y;
                float x2 = (f.z - mr.x) * mr.y * g4.z + b4.z;
                float x3 = (f.w - mr.x) * mr.y * g4.w + b4.w;
                #pragma unroll
                for (int h = 0; h < 8; h++) {
                    float w = wls[h][i];
                    acc[h][0] += w * x0; acc[h][1] += w * x1;
                    acc[h][2] += w * x2; acc[h][3] += w * x3;
                }
            }
            __syncthreads();
        }
    }
    #pragma unroll
    for (int h = 0; h < 8; h++)
        *(uint2*)(hpool + ((size_t)h * BPK_HP_ROWS + bs) * BPK_D + tid * 4) =
            pack4bf(acc[h][0], acc[h][1], acc[h][2], acc[h][3]);
}

// ---------------------------------------------------------------------------
// Kernel 4: per-head GEMM. pooled[bs, h*128+d] = sum_k hpool[h][bs,k]*Wv[h*128+d,k]
// Grid (19 m-tiles, 8 heads); 128x128 tile, BK=32, global_load_lds staging.
// ---------------------------------------------------------------------------
__global__ __launch_bounds__(256) void bpk_headgemm_kernel(
    const bf16* __restrict__ hpool, const bf16* __restrict__ wvb,
    bf16* __restrict__ pooled) {
    const int mt = blockIdx.x, h = blockIdx.y;
    const int m0 = mt * 128;
    const bf16* A = hpool + (size_t)h * BPK_HP_ROWS * BPK_D;
    const bf16* W = wvb + (size_t)(h * 128) * BPK_D;
    __shared__ bf16 As[128][32];
    __shared__ bf16 Bs[128][32];
    const int tid = threadIdx.x;
    const int lane = tid & 63, wid = tid >> 6;
    const int wm = (wid & 1) * 64, wn = (wid >> 1) * 64;
    const int lm = lane & 15, quad = lane >> 4;
    const int c0 = wid * 2;
    const int rA = c0 * 16 + (lane >> 2);
    const int colc = (lane & 3) * 8;

    v4f acc[4][4];
    #pragma unroll
    for (int i = 0; i < 4; i++)
        #pragma unroll
        for (int j = 0; j < 4; j++) acc[i][j] = (v4f){0.f, 0.f, 0.f, 0.f};

    for (int k0 = 0; k0 < BPK_D; k0 += 32) {
        const bf16* pa = &A[(size_t)(m0 + rA) * BPK_D + k0 + colc];
        const bf16* pw = &W[(size_t)rA * BPK_D + k0 + colc];
        BPK_GL2LDS(pa, &As[c0 * 16][0]);
        BPK_GL2LDS(pa + (size_t)16 * BPK_D, &As[(c0 + 1) * 16][0]);
        BPK_GL2LDS(pw, &Bs[c0 * 16][0]);
        BPK_GL2LDS(pw + (size_t)16 * BPK_D, &Bs[(c0 + 1) * 16][0]);
        __syncthreads();
        bf16x8 af[4], bfr[4];
        #pragma unroll
        for (int i = 0; i < 4; i++)
            af[i] = *(const bf16x8*)&As[wm + i * 16 + lm][quad * 8];
        #pragma unroll
        for (int j = 0; j < 4; j++)
            bfr[j] = *(const bf16x8*)&Bs[wn + j * 16 + lm][quad * 8];
        #pragma unroll
        for (int i = 0; i < 4; i++)
            #pragma unroll
            for (int j = 0; j < 4; j++)
                acc[i][j] = __builtin_amdgcn_mfma_f32_16x16x32_bf16(af[i], bfr[j], acc[i][j], 0, 0, 0);
        __syncthreads();
    }
    #pragma unroll
    for (int i = 0; i < 4; i++) {
        int mbase = m0 + wm + i * 16 + quad * 4;
        #pragma unroll
        for (int j = 0; j < 4; j++) {
            int col = h * 128 + wn + j * 16 + lm;
            #pragma unroll
            for (int r = 0; r < 4; r++) {
                int m = mbase + r;
                if (m < BPK_MS)
                    pooled[(size_t)m * BPK_D + col] = __float2bfloat16(acc[i][j][r]);
            }
        }
    }
}

// ---------------------------------------------------------------------------
// Kernel 5: O-GEMM out[m,n] = sum_k pooled[m,k]*Wo[n,k]. XCD-swizzled flat
// grid (NT n-tiles consecutive per XCD). fp32 output, guard m<M.
// ---------------------------------------------------------------------------
template <typename OT>
__global__ __launch_bounds__(256) void bpk_gemm_bt_kernel(
    const bf16* __restrict__ A, const bf16* __restrict__ W,
    OT* __restrict__ O, int M, int NT) {
    const int flat = blockIdx.x;
    const int xcd = flat & 7, slot = flat >> 3;
    const int mt = xcd + 8 * (slot / NT);
    const int nt = slot % NT;
    const int n0 = nt * 128;
    const int m0 = mt * 128;
    __shared__ bf16 As[128][32];
    __shared__ bf16 Bs[128][32];
    const int tid = threadIdx.x;
    const int lane = tid & 63, wid = tid >> 6;
    const int wm = (wid & 1) * 64, wn = (wid >> 1) * 64;
    const int lm = lane & 15, quad = lane >> 4;
    const int c0 = wid * 2;
    const int rA = c0 * 16 + (lane >> 2);
    const int colc = (lane & 3) * 8;

    v4f acc[4][4];
    #pragma unroll
    for (int i = 0; i < 4; i++)
        #pragma unroll
        for (int j = 0; j < 4; j++) acc[i][j] = (v4f){0.f, 0.f, 0.f, 0.f};

    for (int k0 = 0; k0 < BPK_D; k0 += 32) {
        const bf16* pa = &A[(size_t)(m0 + rA) * BPK_D + k0 + colc];
        const bf16* pw = &W[(size_t)(n0 + rA) * BPK_D + k0 + colc];
        BPK_GL2LDS(pa, &As[c0 * 16][0]);
        BPK_GL2LDS(pa + (size_t)16 * BPK_D, &As[(c0 + 1) * 16][0]);
        BPK_GL2LDS(pw, &Bs[c0 * 16][0]);
        BPK_GL2LDS(pw + (size_t)16 * BPK_D, &Bs[(c0 + 1) * 16][0]);
        __syncthreads();
        bf16x8 af[4], bfr[4];
        #pragma unroll
        for (int i = 0; i < 4; i++)
            af[i] = *(const bf16x8*)&As[wm + i * 16 + lm][quad * 8];
        #pragma unroll
        for (int j = 0; j < 4; j++)
            bfr[j] = *(const bf16x8*)&Bs[wn + j * 16 + lm][quad * 8];
        #pragma unroll
        for (int i = 0; i < 4; i++)
            #pragma unroll
            for (int j = 0; j < 4; j++)
                acc[i][j] = __builtin_amdgcn_mfma_f32_16x16x32_bf16(af[i], bfr[j], acc[i][j], 0, 0, 0);
        __syncthreads();
    }
    #pragma unroll
    for (int i = 0; i < 4; i++) {
        int mbase = m0 + wm + i * 16 + quad * 4;
        #pragma unroll
        for (int j = 0; j < 4; j++) {
            int col = n0 + wn + j * 16 + lm;
            #pragma unroll
            for (int r = 0; r < 4; r++) {
                int m = mbase + r;
                if (m < M) bpk_store(acc[i][j][r], &O[(size_t)m * BPK_D + col]);
            }
        }
    }
}

// ---------------------------------------------------------------------------
extern "C" void kernel_launch(void* const* d_in, const int* in_sizes, int n_in,
                              void* d_out, int out_size, void* d_ws, size_t ws_size,
                              hipStream_t stream) {
    const float* hidden     = (const float*)d_in[0];
    const float* boundaries = (const float*)d_in[1];
    const float* lengths    = (const float*)d_in[2];
    const float* lq         = (const float*)d_in[3];
    const float* Wk         = (const float*)d_in[4];
    const float* Wv         = (const float*)d_in[5];
    const float* Wo         = (const float*)d_in[6];
    const float* gamma      = (const float*)d_in[7];
    const float* beta       = (const float*)d_in[8];
    float* out              = (float*)d_out;

    char* ws = (char*)d_ws;
    size_t off = 0;
    auto carve = [&](size_t bytes) -> char* {
        char* p = ws + off;
        off += (bytes + 255) & ~(size_t)255;
        return p;
    };
    bf16* hpool    = (bf16*)carve((size_t)BPK_H * BPK_HP_ROWS * BPK_D * sizeof(bf16)); // 39.8 MB
    bf16* pooled   = (bf16*)carve((size_t)BPK_PO_PAD * BPK_D * sizeof(bf16));          // 6.3 MB
    bf16* wvb      = (bf16*)carve((size_t)BPK_D * BPK_D * sizeof(bf16));
    bf16* wob      = (bf16*)carve((size_t)BPK_D * BPK_D * sizeof(bf16));
    bf16* qkb      = (bf16*)carve((size_t)BPK_H * BPK_D * sizeof(bf16));
    float* scores  = (float*)carve((size_t)BPK_B * BPK_H * BPK_L * sizeof(float));
    float2* murs   = (float2*)carve((size_t)BPK_M * sizeof(float2));
    int* seg_start = (int*)carve((size_t)BPK_B * BPK_S * sizeof(int));
    int* seg_cnt   = (int*)carve((size_t)BPK_B * BPK_S * sizeof(int));

    bpk_prep_kernel<<<dim3(2088), dim3(256), 0, stream>>>(
        Wv, Wo, lq, Wk, boundaries, lengths, wvb, wob, qkb, seg_start, seg_cnt);
    bpk_ln_score_kernel<<<dim3(1024), dim3(256), 0, stream>>>(
        hidden, gamma, beta, qkb, lengths, murs, scores);
    bpk_pool_kernel<<<dim3(BPK_MS), dim3(256), 0, stream>>>(
        scores, hidden, gamma, beta, murs, seg_start, seg_cnt, hpool);
    bpk_headgemm_kernel<<<dim3(BPK_MS_TILES, BPK_H), dim3(256), 0, stream>>>(
        hpool, wvb, pooled);
    bpk_gemm_bt_kernel<float><<<dim3((BPK_PO_PAD / 128) * 8), dim3(256), 0, stream>>>(
        pooled, wob, out, BPK_MS, 8);
}

// Round 11
// 173.896 us; speedup vs baseline: 1.1025x; 1.1025x over previous
//
#include <hip/hip_runtime.h>
#include <hip/hip_bf16.h>

// BoundaryPredictor2: B=8, L=1500, D=1024, H=8, HD=128, S=300. fp32 in/out.
// Pipeline (5 dispatches):
//   1. prep: qk = q@Wk (bf16) + per-batch segment scan (40 blocks)
//   2. ln_score_conv: wave-per-row LN stats + 8 head scores (blocks <1024);
//      blocks >=1024 convert Wv/Wo fp32->bf16 (overlaps the latency-bound
//      score phase instead of serializing ahead of it)
//   3. pool: per-(b,s) softmax + weighted accumulation of re-normalized
//      fp32 hidden rows into per-head hpool
//   4. headgemm (64x64 tiles, 608 blocks): pooled = hpool_h @ Wv_h^T
//   5. ogemm  (64x64 tiles, 640 blocks, XCD swizzle): out = pooled @ Wo^T
// V-GEMM eliminated (pooling commutes with V-proj); K-GEMM eliminated (qk).
// Round-10 history: 128-tile tail GEMMs were 0.6-0.75 blocks/CU (latency-
// bound); 64-tiles quadruple the block count.
#define BPK_B 8
#define BPK_L 1500
#define BPK_D 1024
#define BPK_H 8
#define BPK_S 300
#define BPK_EPS 1e-5f
#define BPK_M (BPK_B * BPK_L)      // 12000 token rows
#define BPK_MS (BPK_B * BPK_S)     // 2400 pooled rows
#define BPK_HP_ROWS 2432           // 38*64 rows per head (hpool padding)
#define BPK_PO_PAD 2560            // 40*64 rows (ogemm A pad; 40 % 8 == 0)

typedef __hip_bfloat16 bf16;
typedef __bf16 bf16x8 __attribute__((ext_vector_type(8)));
typedef float v4f __attribute__((ext_vector_type(4)));

static __device__ __forceinline__ float bf_lo(unsigned u) {
    return __uint_as_float((u & 0xffffu) << 16);
}
static __device__ __forceinline__ float bf_hi(unsigned u) {
    return __uint_as_float((u >> 16) << 16);
}
static __device__ __forceinline__ void bpk_store(float v, float* p) { *p = v; }
static __device__ __forceinline__ void bpk_store(float v, bf16* p) { *p = __float2bfloat16(v); }
static __device__ __forceinline__ uint2 pack4bf(float a, float b, float c, float d) {
    union { bf16 h[4]; uint2 u; } pk;
    pk.h[0] = __float2bfloat16(a); pk.h[1] = __float2bfloat16(b);
    pk.h[2] = __float2bfloat16(c); pk.h[3] = __float2bfloat16(d);
    return pk.u;
}

// async global->LDS, 16B per lane, lds dest = wave-uniform base + lane*16
#define BPK_GL2LDS(gsrc, ldst)                                                 \
    __builtin_amdgcn_global_load_lds(                                          \
        (const __attribute__((address_space(1))) void*)(gsrc),                 \
        (__attribute__((address_space(3))) void*)(ldst), 16, 0, 0)

// ---------------------------------------------------------------------------
// Kernel 1: prep. blocks 0..31: qk[h,:] = sum_d lq[h*128+d]*Wk[h*128+d,:]
// (bf16); blocks 32..39: per-batch parallel segment scan.
// ---------------------------------------------------------------------------
__global__ __launch_bounds__(256) void bpk_prep_kernel(
    const float* __restrict__ lq, const float* __restrict__ Wk,
    const float* __restrict__ boundaries, const float* __restrict__ lengths,
    bf16* __restrict__ qkb, int* __restrict__ seg_start, int* __restrict__ seg_cnt) {
    __shared__ unsigned char flags[1536];
    __shared__ int st_sh[BPK_S + 2];
    __shared__ int wsumi[4];
    int blk = blockIdx.x;
    int tid = threadIdx.x;
    if (blk < 32) {
        int o = blk * 256 + tid;                // 0..8191
        int h = o >> 10, k = o & 1023;
        const float* wr = Wk + (size_t)(h * 128) * BPK_D + k;
        const float* qr = lq + h * 128;
        float s = 0.f;
        #pragma unroll 8
        for (int d = 0; d < 128; d++)
            s += qr[d] * wr[(size_t)d * BPK_D];
        qkb[o] = __float2bfloat16(s);
        return;
    }
    // segment scan, b = blk - 32
    int b = blk - 32;
    int alen = (int)(lengths[b] * (float)BPK_L);   // trunc == .astype(int32)
    const float* bd = boundaries + (size_t)b * BPK_L;
    for (int t = tid; t < 1536; t += 256)
        flags[t] = (t < BPK_L && bd[t] >= 0.5f) ? 1 : 0;
    for (int s = tid; s < BPK_S + 2; s += 256) st_sh[s] = BPK_L;
    __syncthreads();
    int base = tid * 6;
    int lsum = 0;
    #pragma unroll
    for (int j = 0; j < 6; j++) lsum += flags[base + j];
    int lane = tid & 63, wid = tid >> 6;
    int scan = lsum;
    #pragma unroll
    for (int off = 1; off < 64; off <<= 1) {
        int u = __shfl_up(scan, off);
        if (lane >= off) scan += u;
    }
    if (lane == 63) wsumi[wid] = scan;
    __syncthreads();
    int wbase = 0;
    for (int w = 0; w < wid; w++) wbase += wsumi[w];
    int run = wbase + scan - lsum;
    #pragma unroll
    for (int j = 0; j < 6; j++) {
        int t = base + j;
        if (t < BPK_L) {
            int sid = run;
            if ((t == 0 || flags[t - 1]) && sid <= BPK_S) st_sh[sid] = t;
            if (flags[t]) run++;
        }
    }
    __syncthreads();
    for (int s = tid; s < BPK_S; s += 256) {
        int st = st_sh[s];
        int e = min(st_sh[s + 1], alen);
        int s0 = min(st, alen);
        seg_start[b * BPK_S + s] = st;
        seg_cnt[b * BPK_S + s] = max(0, e - s0);
    }
}

// ---------------------------------------------------------------------------
// Kernel 2: LN stats + fused scores (blocks < 1024, wave-per-row, qk in
// registers, exchange-half transpose reduce) PLUS Wv/Wo fp32->bf16
// conversion (blocks 1024..3071) overlapped in the same dispatch.
// ---------------------------------------------------------------------------
__global__ __launch_bounds__(256) void bpk_ln_score_conv_kernel(
    const float* __restrict__ x, const float* __restrict__ gamma,
    const float* __restrict__ beta, const bf16* __restrict__ qkb,
    const float* __restrict__ lengths,
    const float* __restrict__ Wv, const float* __restrict__ Wo,
    bf16* __restrict__ wvb, bf16* __restrict__ wob,
    float2* __restrict__ murs, float* __restrict__ scores) {
    int tid = threadIdx.x;
    if (blockIdx.x >= 1024) {
        int cb = blockIdx.x - 1024;             // 0..2047
        const float* s = cb < 1024 ? Wv : Wo;
        bf16* d = cb < 1024 ? wvb : wob;
        int i = ((cb & 1023) * 256 + tid) * 4;
        float4 v = *(const float4*)(s + i);
        *(uint2*)(d + i) = pack4bf(v.x, v.y, v.z, v.w);
        return;
    }
    int lane = tid & 63, wid = tid >> 6;
    float4 g[4], bb[4];
    uint2 qk[8][4];
    #pragma unroll
    for (int j = 0; j < 4; j++) {
        g[j]  = *(const float4*)(gamma + j * 256 + lane * 4);
        bb[j] = *(const float4*)(beta + j * 256 + lane * 4);
    }
    #pragma unroll
    for (int h = 0; h < 8; h++)
        #pragma unroll
        for (int j = 0; j < 4; j++)
            qk[h][j] = *(const uint2*)(qkb + h * BPK_D + j * 256 + lane * 4);
    float lv = (lane < BPK_B) ? lengths[lane] : 0.f;
    const bool b0 = (lane & 1) != 0;
    const bool b1 = (lane & 2) != 0;
    const bool b2 = (lane & 4) != 0;
    const int head = 4 * (lane & 1) + (lane & 2) + ((lane >> 2) & 1);

    const int nwaves = 1024 * 4;
    for (int row = blockIdx.x * 4 + wid; row < BPK_M; row += nwaves) {
        int b = row / BPK_L, t = row - b * BPK_L;
        float alenf = __shfl(lv, b);
        if (t >= (int)(alenf * (float)BPK_L)) continue;   // wave-uniform skip
        const float* xr = x + (size_t)row * BPK_D;
        float4 f[4];
        float s = 0.f, sq = 0.f;
        #pragma unroll
        for (int j = 0; j < 4; j++) {
            f[j] = *(const float4*)(xr + j * 256 + lane * 4);
            s  += f[j].x + f[j].y + f[j].z + f[j].w;
            sq += f[j].x * f[j].x + f[j].y * f[j].y
                + f[j].z * f[j].z + f[j].w * f[j].w;
        }
        #pragma unroll
        for (int off = 1; off < 64; off <<= 1) {
            s  += __shfl_xor(s, off);
            sq += __shfl_xor(sq, off);
        }
        float mu = s * (1.0f / BPK_D);
        float var = sq * (1.0f / BPK_D) - mu * mu;
        float rs = rsqrtf(var + BPK_EPS);
        float p[8];
        #pragma unroll
        for (int h = 0; h < 8; h++) p[h] = 0.f;
        #pragma unroll
        for (int j = 0; j < 4; j++) {
            float h0 = (f[j].x - mu) * rs * g[j].x + bb[j].x;
            float h1 = (f[j].y - mu) * rs * g[j].y + bb[j].y;
            float h2 = (f[j].z - mu) * rs * g[j].z + bb[j].z;
            float h3 = (f[j].w - mu) * rs * g[j].w + bb[j].w;
            #pragma unroll
            for (int h = 0; h < 8; h++) {
                uint2 qv = qk[h][j];
                p[h] += h0 * bf_lo(qv.x) + h1 * bf_hi(qv.x)
                      + h2 * bf_lo(qv.y) + h3 * bf_hi(qv.y);
            }
        }
        // exchange-half transpose reduce (10 shfls)
        #pragma unroll
        for (int r = 0; r < 4; r++) {
            float send = b0 ? p[r] : p[r + 4];
            float recv = __shfl_xor(send, 1);
            p[r]     += b0 ? 0.f : recv;
            p[r + 4] += b0 ? recv : 0.f;
        }
        float q0 = b0 ? p[4] : p[0];
        float q1 = b0 ? p[5] : p[1];
        float q2 = b0 ? p[6] : p[2];
        float q3 = b0 ? p[7] : p[3];
        {
            float send = b1 ? q0 : q2;
            float recv = __shfl_xor(send, 2);
            q0 += b1 ? 0.f : recv;
            q2 += b1 ? recv : 0.f;
            send = b1 ? q1 : q3;
            recv = __shfl_xor(send, 2);
            q1 += b1 ? 0.f : recv;
            q3 += b1 ? recv : 0.f;
        }
        float a = b1 ? q2 : q0;
        float c = b1 ? q3 : q1;
        float send = b2 ? a : c;
        float recv = __shfl_xor(send, 4);
        float v = (b2 ? c : a) + recv;
        v += __shfl_xor(v, 8);
        v += __shfl_xor(v, 16);
        v += __shfl_xor(v, 32);
        if (lane < 8) {
            scores[((size_t)b * BPK_H + head) * BPK_L + t] =
                v * 0.088388347648318447f;
        } else if (lane == 8) {
            murs[row] = make_float2(mu, rs);
        }
    }
}

// ---------------------------------------------------------------------------
// Kernel 3: per-(b,s) softmax + weighted pooling into per-head hpool.
// Re-normalizes fp32 hidden rows (L3-resident) via murs + gamma/beta.
// ---------------------------------------------------------------------------
__global__ __launch_bounds__(256) void bpk_pool_kernel(
    const float* __restrict__ scores, const float* __restrict__ x,
    const float* __restrict__ gamma, const float* __restrict__ beta,
    const float2* __restrict__ murs,
    const int* __restrict__ seg_start, const int* __restrict__ seg_cnt,
    bf16* __restrict__ hpool) {
    int bs = blockIdx.x;                // = b*S + s
    int b = bs / BPK_S;
    int tid = threadIdx.x;
    int lane = tid & 63, wid = tid >> 6;
    __shared__ float minv[8][2];
    __shared__ float wls[8][128];
    int cnt = seg_cnt[bs], st = seg_start[bs];
    float4 g4 = *(const float4*)(gamma + tid * 4);
    float4 b4 = *(const float4*)(beta + tid * 4);
    float acc[8][4];
    #pragma unroll
    for (int h = 0; h < 8; h++)
        #pragma unroll
        for (int j = 0; j < 4; j++) acc[h][j] = 0.f;
    if (cnt > 0) {
        if (wid == 0) {
            int h = lane & 7, i0 = lane >> 3;   // 8 lanes per head
            const float* sc = scores + ((size_t)(b * 8 + h)) * BPK_L + st;
            float m = -1e30f;
            for (int i = i0; i < cnt; i += 8) m = fmaxf(m, sc[i]);
            #pragma unroll
            for (int off = 8; off < 64; off <<= 1) m = fmaxf(m, __shfl_xor(m, off));
            float l = 0.f;
            for (int i = i0; i < cnt; i += 8) l += __expf(sc[i] - m);
            #pragma unroll
            for (int off = 8; off < 64; off <<= 1) l += __shfl_xor(l, off);
            if (i0 == 0) { minv[h][0] = m; minv[h][1] = 1.0f / l; }
        }
        __syncthreads();
        for (int cb = 0; cb < cnt; cb += 128) {
            int cc = min(128, cnt - cb);
            int hh = tid >> 5, i0 = (tid & 31) * 4;
            #pragma unroll
            for (int j = 0; j < 4; j++) {
                int i = i0 + j;
                if (i < cc)
                    wls[hh][i] = __expf(scores[((size_t)(b * 8 + hh)) * BPK_L + st + cb + i]
                                        - minv[hh][0]) * minv[hh][1];
            }
            __syncthreads();
            const float* xp = x + (size_t)(b * BPK_L + st + cb) * BPK_D + tid * 4;
            const float2* mp = murs + (size_t)(b * BPK_L + st + cb);
            for (int i = 0; i < cc; i++) {
                float4 f = *(const float4*)(xp + (size_t)i * BPK_D);
                float2 mr = mp[i];
                float x0 = (f.x - mr.x) * mr.y * g4.x + b4.x;
                float x1 = (f.y - mr.x) * mr.y * g4.y + b4.y;
                float x2 = (f.z - mr.x) * mr.y * g4.z + b4.z;
                float x3 = (f.w - mr.x) * mr.y * g4.w + b4.w;
                #pragma unroll
                for (int h = 0; h < 8; h++) {
                    float w = wls[h][i];
                    acc[h][0] += w * x0; acc[h][1] += w * x1;
                    acc[h][2] += w * x2; acc[h][3] += w * x3;
                }
            }
            __syncthreads();
        }
    }
    #pragma unroll
    for (int h = 0; h < 8; h++)
        *(uint2*)(hpool + ((size_t)h * BPK_HP_ROWS + bs) * BPK_D + tid * 4) =
            pack4bf(acc[h][0], acc[h][1], acc[h][2], acc[h][3]);
}

// ---------------------------------------------------------------------------
// Kernel 4: per-head GEMM, 64x64 tiles. Grid (76, 8): blockIdx.x = mt*2+nt,
// head = blockIdx.y. 4 waves each own a 32x32 subtile (2x2 mfma). Each wave
// stages 16 rows of A and B per BK=32 step via global_load_lds.
// ---------------------------------------------------------------------------
__global__ __launch_bounds__(256) void bpk_headgemm_kernel(
    const bf16* __restrict__ hpool, const bf16* __restrict__ wvb,
    bf16* __restrict__ pooled) {
    const int mt = blockIdx.x >> 1, nt = blockIdx.x & 1, h = blockIdx.y;
    const int m0 = mt * 64, n0 = nt * 64;
    const bf16* A = hpool + (size_t)h * BPK_HP_ROWS * BPK_D;
    const bf16* W = wvb + (size_t)(h * 128 + n0) * BPK_D;
    __shared__ bf16 As[64][32];
    __shared__ bf16 Bs[64][32];
    const int tid = threadIdx.x;
    const int lane = tid & 63, wid = tid >> 6;
    const int wm = (wid & 1) * 32, wn = (wid >> 1) * 32;
    const int lm = lane & 15, quad = lane >> 4;
    const int rA = wid * 16 + (lane >> 2);
    const int colc = (lane & 3) * 8;

    v4f acc[2][2];
    #pragma unroll
    for (int i = 0; i < 2; i++)
        #pragma unroll
        for (int j = 0; j < 2; j++) acc[i][j] = (v4f){0.f, 0.f, 0.f, 0.f};

    for (int k0 = 0; k0 < BPK_D; k0 += 32) {
        BPK_GL2LDS(&A[(size_t)(m0 + rA) * BPK_D + k0 + colc], &As[wid * 16][0]);
        BPK_GL2LDS(&W[(size_t)rA * BPK_D + k0 + colc], &Bs[wid * 16][0]);
        __syncthreads();
        bf16x8 af[2], bfr[2];
        #pragma unroll
        for (int i = 0; i < 2; i++)
            af[i] = *(const bf16x8*)&As[wm + i * 16 + lm][quad * 8];
        #pragma unroll
        for (int j = 0; j < 2; j++)
            bfr[j] = *(const bf16x8*)&Bs[wn + j * 16 + lm][quad * 8];
        #pragma unroll
        for (int i = 0; i < 2; i++)
            #pragma unroll
            for (int j = 0; j < 2; j++)
                acc[i][j] = __builtin_amdgcn_mfma_f32_16x16x32_bf16(af[i], bfr[j], acc[i][j], 0, 0, 0);
        __syncthreads();
    }
    #pragma unroll
    for (int i = 0; i < 2; i++) {
        int mbase = m0 + wm + i * 16 + quad * 4;
        #pragma unroll
        for (int j = 0; j < 2; j++) {
            int col = h * 128 + n0 + wn + j * 16 + lm;
            #pragma unroll
            for (int r = 0; r < 4; r++) {
                int m = mbase + r;
                if (m < BPK_MS)
                    pooled[(size_t)m * BPK_D + col] = __float2bfloat16(acc[i][j][r]);
            }
        }
    }
}

// ---------------------------------------------------------------------------
// Kernel 5: O-GEMM, 64x64 tiles, flat 640-block grid with exact XCD swizzle
// (40 m-tiles x 16 n-tiles; 16 n-tiles of one m-tile land consecutively on
// one XCD). pooled pad rows (2400..2559) are poison but finite; outputs
// guarded m < 2400.
// ---------------------------------------------------------------------------
__global__ __launch_bounds__(256) void bpk_ogemm_kernel(
    const bf16* __restrict__ A, const bf16* __restrict__ W,
    float* __restrict__ O) {
    const int flat = blockIdx.x;
    const int xcd = flat & 7, slot = flat >> 3;          // slot 0..79
    const int mt = xcd + 8 * (slot >> 4);                // 0..39
    const int nt = slot & 15;
    const int m0 = mt * 64, n0 = nt * 64;
    __shared__ bf16 As[64][32];
    __shared__ bf16 Bs[64][32];
    const int tid = threadIdx.x;
    const int lane = tid & 63, wid = tid >> 6;
    const int wm = (wid & 1) * 32, wn = (wid >> 1) * 32;
    const int lm = lane & 15, quad = lane >> 4;
    const int rA = wid * 16 + (lane >> 2);
    const int colc = (lane & 3) * 8;

    v4f acc[2][2];
    #pragma unroll
    for (int i = 0; i < 2; i++)
        #pragma unroll
        for (int j = 0; j < 2; j++) acc[i][j] = (v4f){0.f, 0.f, 0.f, 0.f};

    for (int k0 = 0; k0 < BPK_D; k0 += 32) {
        BPK_GL2LDS(&A[(size_t)(m0 + rA) * BPK_D + k0 + colc], &As[wid * 16][0]);
        BPK_GL2LDS(&W[(size_t)(n0 + rA) * BPK_D + k0 + colc], &Bs[wid * 16][0]);
        __syncthreads();
        bf16x8 af[2], bfr[2];
        #pragma unroll
        for (int i = 0; i < 2; i++)
            af[i] = *(const bf16x8*)&As[wm + i * 16 + lm][quad * 8];
        #pragma unroll
        for (int j = 0; j < 2; j++)
            bfr[j] = *(const bf16x8*)&Bs[wn + j * 16 + lm][quad * 8];
        #pragma unroll
        for (int i = 0; i < 2; i++)
            #pragma unroll
            for (int j = 0; j < 2; j++)
                acc[i][j] = __builtin_amdgcn_mfma_f32_16x16x32_bf16(af[i], bfr[j], acc[i][j], 0, 0, 0);
        __syncthreads();
    }
    #pragma unroll
    for (int i = 0; i < 2; i++) {
        int mbase = m0 + wm + i * 16 + quad * 4;
        #pragma unroll
        for (int j = 0; j < 2; j++) {
            int col = n0 + wn + j * 16 + lm;
            #pragma unroll
            for (int r = 0; r < 4; r++) {
                int m = mbase + r;
                if (m < BPK_MS) O[(size_t)m * BPK_D + col] = acc[i][j][r];
            }
        }
    }
}

// ---------------------------------------------------------------------------
extern "C" void kernel_launch(void* const* d_in, const int* in_sizes, int n_in,
                              void* d_out, int out_size, void* d_ws, size_t ws_size,
                              hipStream_t stream) {
    const float* hidden     = (const float*)d_in[0];
    const float* boundaries = (const float*)d_in[1];
    const float* lengths    = (const float*)d_in[2];
    const float* lq         = (const float*)d_in[3];
    const float* Wk         = (const float*)d_in[4];
    const float* Wv         = (const float*)d_in[5];
    const float* Wo         = (const float*)d_in[6];
    const float* gamma      = (const float*)d_in[7];
    const float* beta       = (const float*)d_in[8];
    float* out              = (float*)d_out;

    char* ws = (char*)d_ws;
    size_t off = 0;
    auto carve = [&](size_t bytes) -> char* {
        char* p = ws + off;
        off += (bytes + 255) & ~(size_t)255;
        return p;
    };
    bf16* hpool    = (bf16*)carve((size_t)BPK_H * BPK_HP_ROWS * BPK_D * sizeof(bf16)); // 39.8 MB
    bf16* pooled   = (bf16*)carve((size_t)BPK_PO_PAD * BPK_D * sizeof(bf16));          // 5.2 MB
    bf16* wvb      = (bf16*)carve((size_t)BPK_D * BPK_D * sizeof(bf16));
    bf16* wob      = (bf16*)carve((size_t)BPK_D * BPK_D * sizeof(bf16));
    bf16* qkb      = (bf16*)carve((size_t)BPK_H * BPK_D * sizeof(bf16));
    float* scores  = (float*)carve((size_t)BPK_B * BPK_H * BPK_L * sizeof(float));
    float2* murs   = (float2*)carve((size_t)BPK_M * sizeof(float2));
    int* seg_start = (int*)carve((size_t)BPK_B * BPK_S * sizeof(int));
    int* seg_cnt   = (int*)carve((size_t)BPK_B * BPK_S * sizeof(int));

    bpk_prep_kernel<<<dim3(40), dim3(256), 0, stream>>>(
        lq, Wk, boundaries, lengths, qkb, seg_start, seg_cnt);
    bpk_ln_score_conv_kernel<<<dim3(3072), dim3(256), 0, stream>>>(
        hidden, gamma, beta, qkb, lengths, Wv, Wo, wvb, wob, murs, scores);
    bpk_pool_kernel<<<dim3(BPK_MS), dim3(256), 0, stream>>>(
        scores, hidden, gamma, beta, murs, seg_start, seg_cnt, hpool);
    bpk_headgemm_kernel<<<dim3(76, BPK_H), dim3(256), 0, stream>>>(
        hpool, wvb, pooled);
    bpk_ogemm_kernel<<<dim3(640), dim3(256), 0, stream>>>(
        pooled, wob, out);
}